// Round 2
// baseline (8607.286 us; speedup 1.0000x reference)
//
#include <hip/hip_runtime.h>
#include <hip/hip_bf16.h>
#include <cstddef>

#define B 4
#define S 1024
#define D 1024
#define H 16
#define L 4
#define F 4096
#define V 8192
#define DK 64
#define M (B*S)          // 4096 rows
#define EPS 1e-5f
#define SCALE 0.125f     // 1/sqrt(64)

// ---------------------------------------------------------------------------
// Embedding + sinusoidal positional encoding
// x[b,s,d] = emb[src[b,s]][d] + pe(s,d)
// ---------------------------------------------------------------------------
__global__ void embed_kernel(const int* __restrict__ src,
                             const float* __restrict__ emb,
                             float* __restrict__ x) {
    int idx = blockIdx.x * blockDim.x + threadIdx.x;
    if (idx >= B * S * D) return;
    int d  = idx & (D - 1);
    int bs = idx >> 10;            // b*S + s   (D = 1024)
    int s  = bs & (S - 1);
    int tok = src[bs];
    int d2 = d & ~1;
    // div = exp(d2 * (-ln(10000)/D))
    float div = expf((float)d2 * (-9.210340371976184f / 1024.0f));
    float arg = (float)s * div;
    float pe = (d & 1) ? cosf(arg) : sinf(arg);
    x[idx] = emb[(size_t)tok * D + d] + pe;
}

// ---------------------------------------------------------------------------
// Tiled fp32 GEMM: C[M,N] = A[M,K] @ W[K,N] + bias[N]  (optional ReLU)
// 64x64 tile / block of 256 threads, each thread 4x4, BK=16
// ---------------------------------------------------------------------------
template<bool RELU>
__global__ __launch_bounds__(256) void gemm_kernel(
        const float* __restrict__ A, const float* __restrict__ W,
        const float* __restrict__ bias, float* __restrict__ C,
        int K, int N) {
    __shared__ float As[16][68];   // [k][m], padded: 2-way max conflicts
    __shared__ float Bs[16][64];   // [k][n]

    const int tid = threadIdx.x;
    const int bn = blockIdx.x;
    const int bm = blockIdx.y;
    const int tx = tid & 15;       // 0..15  -> n
    const int ty = tid >> 4;       // 0..15  -> m

    const int arow = tid >> 2;           // 0..63
    const int ak   = (tid & 3) * 4;      // 0,4,8,12
    const int brow = tid >> 4;           // 0..15
    const int bcol = (tid & 15) * 4;     // 0..60

    const float* Ab = A + (size_t)bm * 64 * K;
    const float* Bb = W + (size_t)bn * 64;

    float acc[4][4];
    #pragma unroll
    for (int i = 0; i < 4; ++i)
        #pragma unroll
        for (int j = 0; j < 4; ++j) acc[i][j] = 0.0f;

    for (int k0 = 0; k0 < K; k0 += 16) {
        float4 a4 = *(const float4*)&Ab[(size_t)arow * K + k0 + ak];
        float4 b4 = *(const float4*)&Bb[(size_t)(k0 + brow) * N + bcol];
        __syncthreads();
        As[ak + 0][arow] = a4.x;
        As[ak + 1][arow] = a4.y;
        As[ak + 2][arow] = a4.z;
        As[ak + 3][arow] = a4.w;
        *(float4*)&Bs[brow][bcol] = b4;
        __syncthreads();
        #pragma unroll
        for (int kk = 0; kk < 16; ++kk) {
            float4 av = *(const float4*)&As[kk][ty * 4];
            float4 bv = *(const float4*)&Bs[kk][tx * 4];
            acc[0][0] += av.x * bv.x; acc[0][1] += av.x * bv.y;
            acc[0][2] += av.x * bv.z; acc[0][3] += av.x * bv.w;
            acc[1][0] += av.y * bv.x; acc[1][1] += av.y * bv.y;
            acc[1][2] += av.y * bv.z; acc[1][3] += av.y * bv.w;
            acc[2][0] += av.z * bv.x; acc[2][1] += av.z * bv.y;
            acc[2][2] += av.z * bv.z; acc[2][3] += av.z * bv.w;
            acc[3][0] += av.w * bv.x; acc[3][1] += av.w * bv.y;
            acc[3][2] += av.w * bv.z; acc[3][3] += av.w * bv.w;
        }
    }

    float4 bia = *(const float4*)&bias[bn * 64 + tx * 4];
    #pragma unroll
    for (int i = 0; i < 4; ++i) {
        float4 r;
        r.x = acc[i][0] + bia.x;
        r.y = acc[i][1] + bia.y;
        r.z = acc[i][2] + bia.z;
        r.w = acc[i][3] + bia.w;
        if (RELU) {
            r.x = fmaxf(r.x, 0.0f); r.y = fmaxf(r.y, 0.0f);
            r.z = fmaxf(r.z, 0.0f); r.w = fmaxf(r.w, 0.0f);
        }
        *(float4*)&C[(size_t)(bm * 64 + ty * 4 + i) * N + bn * 64 + tx * 4] = r;
    }
}

// ---------------------------------------------------------------------------
// Flash-style attention (fp32). One block = (b, h, 64-query tile).
// Mask semantics per reference: mask[b,q,k] = (src[b,q]!=0) && (k<=q);
// fully-masked query rows softmax to uniform 1/S over ALL keys, so we do NOT
// skip above-diagonal key tiles.
// ---------------------------------------------------------------------------
__global__ __launch_bounds__(256) void attn_kernel(
        const float* __restrict__ qg, const float* __restrict__ kg,
        const float* __restrict__ vg, const int* __restrict__ src,
        float* __restrict__ ag) {
    __shared__ float Qs[64][68];
    __shared__ float Ks[64][68];
    __shared__ float Vs[64][68];
    __shared__ float Ps[64][68];

    const int tid = threadIdx.x;
    const int qt = blockIdx.x & 15;          // S/64 = 16
    const int h  = (blockIdx.x >> 4) & 15;   // H = 16
    const int b  = blockIdx.x >> 8;
    const int q0 = qt * 64;

    const int lrow = tid >> 4;           // 0..15
    const int ld4  = (tid & 15) * 4;     // 0..60

    // stage Q tile
    for (int r = lrow; r < 64; r += 16)
        *(float4*)&Qs[r][ld4] =
            *(const float4*)&qg[((size_t)(b * S + q0 + r)) * D + h * DK + ld4];

    const int w    = tid >> 6;
    const int lane = tid & 63;
    const int qrow = w * 16 + (lane & 15);
    const int seg  = lane >> 4;          // 0..3
    const int ks0  = seg * 16;
    const int dr0  = seg * 16;
    const int qglob = q0 + qrow;
    const int srcq  = src[b * S + qglob];

    float m = -3.0e38f, lsum = 0.0f;
    float o[16];
    #pragma unroll
    for (int j = 0; j < 16; ++j) o[j] = 0.0f;

    for (int kt = 0; kt < S / 64; ++kt) {
        const int k0 = kt * 64;
        __syncthreads();   // previous iteration done reading Ks/Vs
        for (int r = lrow; r < 64; r += 16) {
            *(float4*)&Ks[r][ld4] =
                *(const float4*)&kg[((size_t)(b * S + k0 + r)) * D + h * DK + ld4];
            *(float4*)&Vs[r][ld4] =
                *(const float4*)&vg[((size_t)(b * S + k0 + r)) * D + h * DK + ld4];
        }
        __syncthreads();

        // scores: this lane -> 1 q-row x 16 keys
        float sc[16];
        #pragma unroll
        for (int kk = 0; kk < 16; ++kk) sc[kk] = 0.0f;
        for (int d0 = 0; d0 < DK; d0 += 4) {
            float4 q4 = *(const float4*)&Qs[qrow][d0];
            #pragma unroll
            for (int kk = 0; kk < 16; ++kk) {
                float4 k4 = *(const float4*)&Ks[ks0 + kk][d0];
                sc[kk] += q4.x * k4.x + q4.y * k4.y + q4.z * k4.z + q4.w * k4.w;
            }
        }
        float tmax = -3.0e38f;
        #pragma unroll
        for (int kk = 0; kk < 16; ++kk) {
            int kglob = k0 + ks0 + kk;
            sc[kk] = (srcq != 0 && kglob <= qglob) ? sc[kk] * SCALE : -1e9f;
            tmax = fmaxf(tmax, sc[kk]);
        }
        tmax = fmaxf(tmax, __shfl_xor(tmax, 16));
        tmax = fmaxf(tmax, __shfl_xor(tmax, 32));
        float mnew = fmaxf(m, tmax);
        float corr = expf(m - mnew);   // first tile: exp(-huge) = 0
        float rsum = 0.0f;
        #pragma unroll
        for (int kk = 0; kk < 16; ++kk) {
            float p = expf(sc[kk] - mnew);
            Ps[qrow][ks0 + kk] = p;
            rsum += p;
        }
        rsum += __shfl_xor(rsum, 16);
        rsum += __shfl_xor(rsum, 32);
        lsum = lsum * corr + rsum;
        m = mnew;
        #pragma unroll
        for (int j = 0; j < 16; ++j) o[j] *= corr;

        // PV: o[q, dr0..dr0+15] += P[q,:] @ V[:, dr0..dr0+15]
        // (Ps rows for this wave were written by this wave only)
        #pragma unroll 4
        for (int kk = 0; kk < 64; ++kk) {
            float p = Ps[qrow][kk];
            float4 v0 = *(const float4*)&Vs[kk][dr0];
            float4 v1 = *(const float4*)&Vs[kk][dr0 + 4];
            float4 v2 = *(const float4*)&Vs[kk][dr0 + 8];
            float4 v3 = *(const float4*)&Vs[kk][dr0 + 12];
            o[0]  += p * v0.x; o[1]  += p * v0.y; o[2]  += p * v0.z; o[3]  += p * v0.w;
            o[4]  += p * v1.x; o[5]  += p * v1.y; o[6]  += p * v1.z; o[7]  += p * v1.w;
            o[8]  += p * v2.x; o[9]  += p * v2.y; o[10] += p * v2.z; o[11] += p * v2.w;
            o[12] += p * v3.x; o[13] += p * v3.y; o[14] += p * v3.z; o[15] += p * v3.w;
        }
    }

    float inv = 1.0f / lsum;
    #pragma unroll
    for (int j0 = 0; j0 < 16; j0 += 4) {
        float4 r;
        r.x = o[j0 + 0] * inv; r.y = o[j0 + 1] * inv;
        r.z = o[j0 + 2] * inv; r.w = o[j0 + 3] * inv;
        *(float4*)&ag[((size_t)(b * S + qglob)) * D + h * DK + dr0 + j0] = r;
    }
}

// ---------------------------------------------------------------------------
// x = LayerNorm(x + r) * g + beta   (in place on x; one block per row)
// ---------------------------------------------------------------------------
__global__ __launch_bounds__(256) void add_ln_kernel(
        float* __restrict__ x, const float* __restrict__ r,
        const float* __restrict__ g, const float* __restrict__ be) {
    __shared__ float red[8];
    const int row = blockIdx.x;
    const size_t off = (size_t)row * D;
    const int t = threadIdx.x;
    const int w = t >> 6, lane = t & 63;

    float4 xv = *(float4*)&x[off + t * 4];
    float4 rv = *(const float4*)&r[off + t * 4];
    float v0 = xv.x + rv.x, v1 = xv.y + rv.y, v2 = xv.z + rv.z, v3 = xv.w + rv.w;

    float s = v0 + v1 + v2 + v3;
    #pragma unroll
    for (int msk = 1; msk < 64; msk <<= 1) s += __shfl_xor(s, msk);
    if (lane == 0) red[w] = s;
    __syncthreads();
    float mean = (red[0] + red[1] + red[2] + red[3]) * (1.0f / D);

    float d0 = v0 - mean, d1 = v1 - mean, d2 = v2 - mean, d3 = v3 - mean;
    float sq = d0 * d0 + d1 * d1 + d2 * d2 + d3 * d3;
    #pragma unroll
    for (int msk = 1; msk < 64; msk <<= 1) sq += __shfl_xor(sq, msk);
    if (lane == 0) red[4 + w] = sq;
    __syncthreads();
    float var = (red[4] + red[5] + red[6] + red[7]) * (1.0f / D);
    float inv = rsqrtf(var + EPS);

    float4 gv = *(const float4*)&g[t * 4];
    float4 bv = *(const float4*)&be[t * 4];
    float4 out;
    out.x = gv.x * d0 * inv + bv.x;
    out.y = gv.y * d1 * inv + bv.y;
    out.z = gv.z * d2 * inv + bv.z;
    out.w = gv.w * d3 * inv + bv.w;
    *(float4*)&x[off + t * 4] = out;
}

// ---------------------------------------------------------------------------
extern "C" void kernel_launch(void* const* d_in, const int* in_sizes, int n_in,
                              void* d_out, int out_size, void* d_ws, size_t ws_size,
                              hipStream_t stream) {
    (void)in_sizes; (void)n_in; (void)out_size; (void)ws_size;

    const int*   src  = (const int*)  d_in[0];
    const float* emb  = (const float*)d_in[1];
    const float* Wq   = (const float*)d_in[2];
    const float* bq   = (const float*)d_in[3];
    const float* Wk   = (const float*)d_in[4];
    const float* bk   = (const float*)d_in[5];
    const float* Wv   = (const float*)d_in[6];
    const float* bv   = (const float*)d_in[7];
    const float* Wo   = (const float*)d_in[8];
    const float* bo   = (const float*)d_in[9];
    const float* W1   = (const float*)d_in[10];
    const float* b1   = (const float*)d_in[11];
    const float* W2   = (const float*)d_in[12];
    const float* b2   = (const float*)d_in[13];
    const float* g1   = (const float*)d_in[14];
    const float* be1  = (const float*)d_in[15];
    const float* g3   = (const float*)d_in[16];
    const float* be3  = (const float*)d_in[17];
    const float* Wf   = (const float*)d_in[18];
    const float* bf   = (const float*)d_in[19];

    float* ws = (float*)d_ws;
    const size_t MD = (size_t)M * D;      // 4,194,304
    float* x  = ws;                       // [M,D]
    float* qb = ws + 1 * MD;              // [M,D]
    float* kb = ws + 2 * MD;              // [M,D]
    float* vb = ws + 3 * MD;              // [M,D]
    float* ab = ws + 4 * MD;              // [M,D]
    float* pb = ws + 5 * MD;              // [M,D]
    float* f1 = ws + 1 * MD;              // [M,F] aliases qb..ab (dead then)

    embed_kernel<<<(B * S * D + 255) / 256, 256, 0, stream>>>(src, emb, x);

    const dim3 blk(256);
    const dim3 gDD(D / 64, M / 64);
    const dim3 gDF(F / 64, M / 64);
    const dim3 gFD(D / 64, M / 64);
    const dim3 gDV(V / 64, M / 64);

    for (int l = 0; l < L; ++l) {
        const size_t oDD = (size_t)l * D * D;
        gemm_kernel<false><<<gDD, blk, 0, stream>>>(x,  Wq + oDD, bq + l * D, qb, D, D);
        gemm_kernel<false><<<gDD, blk, 0, stream>>>(x,  Wk + oDD, bk + l * D, kb, D, D);
        gemm_kernel<false><<<gDD, blk, 0, stream>>>(x,  Wv + oDD, bv + l * D, vb, D, D);
        attn_kernel<<<B * H * (S / 64), blk, 0, stream>>>(qb, kb, vb, src, ab);
        gemm_kernel<false><<<gDD, blk, 0, stream>>>(ab, Wo + oDD, bo + l * D, pb, D, D);
        add_ln_kernel<<<M, blk, 0, stream>>>(x, pb, g1 + l * D, be1 + l * D);
        gemm_kernel<true ><<<gDF, blk, 0, stream>>>(x,  W1 + (size_t)l * D * F, b1 + l * F, f1, D, F);
        gemm_kernel<false><<<gFD, blk, 0, stream>>>(f1, W2 + (size_t)l * F * D, b2 + l * D, pb, F, D);
        add_ln_kernel<<<M, blk, 0, stream>>>(x, pb, g3 + l * D, be3 + l * D);
    }

    gemm_kernel<false><<<gDV, blk, 0, stream>>>(x, Wf, bf, (float*)d_out, D, V);
}

// Round 3
// 3185.495 us; speedup vs baseline: 2.7020x; 2.7020x over previous
//
#include <hip/hip_runtime.h>
#include <hip/hip_bf16.h>
#include <cstddef>
#include <cstdint>

#define B 4
#define S 1024
#define D 1024
#define H 16
#define L 4
#define F 4096
#define V 8192
#define DK 64
#define M (B*S)          // 4096 rows
#define EPS 1e-5f
#define SCALE 0.125f     // 1/sqrt(64)

typedef __bf16 bf16x8 __attribute__((ext_vector_type(8)));
typedef __bf16 bf16x4 __attribute__((ext_vector_type(4)));
typedef float  f32x4  __attribute__((ext_vector_type(4)));

// async global->LDS, 16B per lane; LDS dest = wave-uniform base + lane*16
__device__ __forceinline__ void gload16(const void* g, void* l) {
    __builtin_amdgcn_global_load_lds(
        (const __attribute__((address_space(1))) void*)g,
        (__attribute__((address_space(3))) void*)l, 16, 0, 0);
}

// ---------------------------------------------------------------------------
// Embedding + sinusoidal positional encoding (dual fp32 + bf16 output)
// ---------------------------------------------------------------------------
__global__ void embed_kernel(const int* __restrict__ src,
                             const float* __restrict__ emb,
                             float* __restrict__ x, __bf16* __restrict__ xbf) {
    int idx = blockIdx.x * blockDim.x + threadIdx.x;
    if (idx >= B * S * D) return;
    int d  = idx & (D - 1);
    int bs = idx >> 10;
    int s  = bs & (S - 1);
    int tok = src[bs];
    int d2 = d & ~1;
    float div = expf((float)d2 * (-9.210340371976184f / 1024.0f));
    float arg = (float)s * div;
    float pe = (d & 1) ? cosf(arg) : sinf(arg);
    float v = emb[(size_t)tok * D + d] + pe;
    x[idx] = v;
    xbf[idx] = (__bf16)v;
}

// ---------------------------------------------------------------------------
// fp32 [K][N]  ->  bf16 [N][K]   (weight transpose + downconvert)
// grid = (N/64, K/64), block = 256
// ---------------------------------------------------------------------------
__global__ __launch_bounds__(256) void transpose_bf16_kernel(
        const float* __restrict__ in, __bf16* __restrict__ out, int K, int N) {
    __shared__ float tile[64][65];
    const int n0 = blockIdx.x * 64, k0 = blockIdx.y * 64;
    const int r = threadIdx.x >> 4, c4 = (threadIdx.x & 15) * 4;
    #pragma unroll
    for (int p = 0; p < 4; ++p) {
        float4 v = *(const float4*)&in[(size_t)(k0 + r + p * 16) * N + n0 + c4];
        tile[r + p * 16][c4 + 0] = v.x;
        tile[r + p * 16][c4 + 1] = v.y;
        tile[r + p * 16][c4 + 2] = v.z;
        tile[r + p * 16][c4 + 3] = v.w;
    }
    __syncthreads();
    #pragma unroll
    for (int p = 0; p < 4; ++p) {
        int n = r + p * 16;
        bf16x4 o = { (__bf16)tile[c4 + 0][n], (__bf16)tile[c4 + 1][n],
                     (__bf16)tile[c4 + 2][n], (__bf16)tile[c4 + 3][n] };
        *(bf16x4*)&out[(size_t)(n0 + n) * K + k0 + c4] = o;
    }
}

__global__ void pack_qkv_bias_kernel(const float* __restrict__ bq,
                                     const float* __restrict__ bk,
                                     const float* __restrict__ bv,
                                     float* __restrict__ o) {
    int i = blockIdx.x * 256 + threadIdx.x;
    if (i >= 3 * D) return;
    o[i] = (i < D) ? bq[i] : (i < 2 * D) ? bk[i - D] : bv[i - 2 * D];
}

// ---------------------------------------------------------------------------
// MFMA bf16 GEMM (m97 structure): C[M,N] = A[M,K] @ BT[N,K]^T + bias
// 128x128 tile, BK=32, 256 thr = 4 waves (2x2), each wave 64x64 via 4x4
// mfma_f32_16x16x32_bf16 fragments. global_load_lds width 16 staging.
// ---------------------------------------------------------------------------
template<bool RELU, bool OBF>
__global__ __launch_bounds__(256) void mfma_gemm(
        const __bf16* __restrict__ A, const __bf16* __restrict__ BT,
        const float* __restrict__ bias, void* __restrict__ Cout,
        int N, int K) {
    __shared__ __bf16 Asl[128 * 32];
    __shared__ __bf16 Bsl[128 * 32];

    const int tid = threadIdx.x;
    const int bn = blockIdx.x, bm = blockIdx.y;
    const int wv = tid >> 6, ln = tid & 63;
    const int wr = wv >> 1, wc = wv & 1;
    const int fr = ln & 15, kq = ln >> 4;

    // staging: chunk c = tid covers row c>>2 (0..63), bytes (c&3)*16 of the
    // 64B K-slab; chunk tid+256 covers rows 64..127.
    const __bf16* Ag = A + (size_t)(bm * 128 + (tid >> 2)) * K + (tid & 3) * 8;
    const __bf16* Bg = BT + (size_t)(bn * 128 + (tid >> 2)) * K + (tid & 3) * 8;
    char* AsW = (char*)Asl + wv * 1024;     // wave-uniform LDS base
    char* BsW = (char*)Bsl + wv * 1024;

    f32x4 acc[4][4];
    #pragma unroll
    for (int i = 0; i < 4; ++i)
        #pragma unroll
        for (int j = 0; j < 4; ++j) acc[i][j] = f32x4{0.f, 0.f, 0.f, 0.f};

    const size_t K64 = (size_t)64 * K;
    for (int k0 = 0; k0 < K; k0 += 32) {
        __syncthreads();                    // prev compute done reading LDS
        gload16(Ag + k0,       AsW);
        gload16(Ag + K64 + k0, AsW + 4096);
        gload16(Bg + k0,       BsW);
        gload16(Bg + K64 + k0, BsW + 4096);
        __syncthreads();                    // drains vmcnt(0): LDS ready

        bf16x8 af[4], bfr[4];
        const char* Ab = (const char*)Asl;
        const char* Bb = (const char*)Bsl;
        #pragma unroll
        for (int mi = 0; mi < 4; ++mi)
            af[mi] = *(const bf16x8*)(Ab + (wr * 64 + mi * 16 + fr) * 64 + kq * 16);
        #pragma unroll
        for (int ni = 0; ni < 4; ++ni)
            bfr[ni] = *(const bf16x8*)(Bb + (wc * 64 + ni * 16 + fr) * 64 + kq * 16);
        #pragma unroll
        for (int mi = 0; mi < 4; ++mi)
            #pragma unroll
            for (int ni = 0; ni < 4; ++ni)
                acc[mi][ni] = __builtin_amdgcn_mfma_f32_16x16x32_bf16(
                                  af[mi], bfr[ni], acc[mi][ni], 0, 0, 0);
    }

    // epilogue: C/D layout col=lane&15, row=(lane>>4)*4+reg
    const int col0 = bn * 128 + wc * 64;
    const int row0 = bm * 128 + wr * 64;
    #pragma unroll
    for (int ni = 0; ni < 4; ++ni) {
        const int col = col0 + ni * 16 + fr;
        const float bia = bias[col];
        #pragma unroll
        for (int mi = 0; mi < 4; ++mi)
            #pragma unroll
            for (int j = 0; j < 4; ++j) {
                const int row = row0 + mi * 16 + kq * 4 + j;
                float v = acc[mi][ni][j] + bia;
                if (RELU) v = fmaxf(v, 0.f);
                if (OBF) ((__bf16*)Cout)[(size_t)row * N + col] = (__bf16)v;
                else     ((float*)Cout)[(size_t)row * N + col] = v;
            }
    }
}

// ---------------------------------------------------------------------------
// Flash-style attention, fp32 math, bf16 QKV input [M][3*D], bf16 output.
// Mask per reference: mask[b,q,k] = (src[b,q]!=0) && (k<=q); fully-masked
// rows softmax to uniform over ALL keys -> visit every key tile.
// ---------------------------------------------------------------------------
__global__ __launch_bounds__(256) void attn_kernel(
        const __bf16* __restrict__ qkv, const int* __restrict__ src,
        __bf16* __restrict__ ag) {
    __shared__ float Qs[64][68];
    __shared__ float Ks[64][68];
    __shared__ float Vs[64][68];
    __shared__ float Ps[64][68];

    const int tid = threadIdx.x;
    const int qt = blockIdx.x & 15;
    const int h  = (blockIdx.x >> 4) & 15;
    const int b  = blockIdx.x >> 8;
    const int q0 = qt * 64;

    const int lrow = tid >> 4;
    const int ld4  = (tid & 15) * 4;
    const int qoff = h * DK, koff = D + h * DK, voff = 2 * D + h * DK;

    for (int r = lrow; r < 64; r += 16) {
        bf16x4 v = *(const bf16x4*)&qkv[(size_t)(b * S + q0 + r) * (3 * D) + qoff + ld4];
        float4 f = { (float)v[0], (float)v[1], (float)v[2], (float)v[3] };
        *(float4*)&Qs[r][ld4] = f;
    }

    const int w    = tid >> 6;
    const int lane = tid & 63;
    const int qrow = w * 16 + (lane & 15);
    const int seg  = lane >> 4;
    const int ks0  = seg * 16;
    const int dr0  = seg * 16;
    const int qglob = q0 + qrow;
    const int srcq  = src[b * S + qglob];

    float m = -3.0e38f, lsum = 0.0f;
    float o[16];
    #pragma unroll
    for (int j = 0; j < 16; ++j) o[j] = 0.0f;

    for (int kt = 0; kt < S / 64; ++kt) {
        const int k0 = kt * 64;
        __syncthreads();
        for (int r = lrow; r < 64; r += 16) {
            bf16x4 kv = *(const bf16x4*)&qkv[(size_t)(b * S + k0 + r) * (3 * D) + koff + ld4];
            bf16x4 vv = *(const bf16x4*)&qkv[(size_t)(b * S + k0 + r) * (3 * D) + voff + ld4];
            float4 kf = { (float)kv[0], (float)kv[1], (float)kv[2], (float)kv[3] };
            float4 vf = { (float)vv[0], (float)vv[1], (float)vv[2], (float)vv[3] };
            *(float4*)&Ks[r][ld4] = kf;
            *(float4*)&Vs[r][ld4] = vf;
        }
        __syncthreads();

        float sc[16];
        #pragma unroll
        for (int kk = 0; kk < 16; ++kk) sc[kk] = 0.0f;
        for (int d0 = 0; d0 < DK; d0 += 4) {
            float4 q4 = *(const float4*)&Qs[qrow][d0];
            #pragma unroll
            for (int kk = 0; kk < 16; ++kk) {
                float4 k4 = *(const float4*)&Ks[ks0 + kk][d0];
                sc[kk] += q4.x * k4.x + q4.y * k4.y + q4.z * k4.z + q4.w * k4.w;
            }
        }
        float tmax = -3.0e38f;
        #pragma unroll
        for (int kk = 0; kk < 16; ++kk) {
            int kglob = k0 + ks0 + kk;
            sc[kk] = (srcq != 0 && kglob <= qglob) ? sc[kk] * SCALE : -1e9f;
            tmax = fmaxf(tmax, sc[kk]);
        }
        tmax = fmaxf(tmax, __shfl_xor(tmax, 16));
        tmax = fmaxf(tmax, __shfl_xor(tmax, 32));
        float mnew = fmaxf(m, tmax);
        float corr = expf(m - mnew);
        float rsum = 0.0f;
        #pragma unroll
        for (int kk = 0; kk < 16; ++kk) {
            float p = expf(sc[kk] - mnew);
            Ps[qrow][ks0 + kk] = p;
            rsum += p;
        }
        rsum += __shfl_xor(rsum, 16);
        rsum += __shfl_xor(rsum, 32);
        lsum = lsum * corr + rsum;
        m = mnew;
        #pragma unroll
        for (int j = 0; j < 16; ++j) o[j] *= corr;

        #pragma unroll 4
        for (int kk = 0; kk < 64; ++kk) {
            float p = Ps[qrow][kk];
            float4 v0 = *(const float4*)&Vs[kk][dr0];
            float4 v1 = *(const float4*)&Vs[kk][dr0 + 4];
            float4 v2 = *(const float4*)&Vs[kk][dr0 + 8];
            float4 v3 = *(const float4*)&Vs[kk][dr0 + 12];
            o[0]  += p * v0.x; o[1]  += p * v0.y; o[2]  += p * v0.z; o[3]  += p * v0.w;
            o[4]  += p * v1.x; o[5]  += p * v1.y; o[6]  += p * v1.z; o[7]  += p * v1.w;
            o[8]  += p * v2.x; o[9]  += p * v2.y; o[10] += p * v2.z; o[11] += p * v2.w;
            o[12] += p * v3.x; o[13] += p * v3.y; o[14] += p * v3.z; o[15] += p * v3.w;
        }
    }

    float inv = 1.0f / lsum;
    #pragma unroll
    for (int j0 = 0; j0 < 16; j0 += 4) {
        bf16x4 r = { (__bf16)(o[j0 + 0] * inv), (__bf16)(o[j0 + 1] * inv),
                     (__bf16)(o[j0 + 2] * inv), (__bf16)(o[j0 + 3] * inv) };
        *(bf16x4*)&ag[(size_t)(b * S + qglob) * D + h * DK + dr0 + j0] = r;
    }
}

// ---------------------------------------------------------------------------
// x = LayerNorm(x + r) * g + beta  (in place, fp32) + bf16 copy
// ---------------------------------------------------------------------------
__global__ __launch_bounds__(256) void add_ln_kernel(
        float* __restrict__ x, const float* __restrict__ r,
        const float* __restrict__ g, const float* __restrict__ be,
        __bf16* __restrict__ xbf) {
    __shared__ float red[8];
    const int row = blockIdx.x;
    const size_t off = (size_t)row * D;
    const int t = threadIdx.x;
    const int w = t >> 6, lane = t & 63;

    float4 xv = *(float4*)&x[off + t * 4];
    float4 rv = *(const float4*)&r[off + t * 4];
    float v0 = xv.x + rv.x, v1 = xv.y + rv.y, v2 = xv.z + rv.z, v3 = xv.w + rv.w;

    float s = v0 + v1 + v2 + v3;
    #pragma unroll
    for (int msk = 1; msk < 64; msk <<= 1) s += __shfl_xor(s, msk);
    if (lane == 0) red[w] = s;
    __syncthreads();
    float mean = (red[0] + red[1] + red[2] + red[3]) * (1.0f / D);

    float d0 = v0 - mean, d1 = v1 - mean, d2 = v2 - mean, d3 = v3 - mean;
    float sq = d0 * d0 + d1 * d1 + d2 * d2 + d3 * d3;
    #pragma unroll
    for (int msk = 1; msk < 64; msk <<= 1) sq += __shfl_xor(sq, msk);
    if (lane == 0) red[4 + w] = sq;
    __syncthreads();
    float var = (red[4] + red[5] + red[6] + red[7]) * (1.0f / D);
    float inv = rsqrtf(var + EPS);

    float4 gv = *(const float4*)&g[t * 4];
    float4 bv = *(const float4*)&be[t * 4];
    float4 out;
    out.x = gv.x * d0 * inv + bv.x;
    out.y = gv.y * d1 * inv + bv.y;
    out.z = gv.z * d2 * inv + bv.z;
    out.w = gv.w * d3 * inv + bv.w;
    *(float4*)&x[off + t * 4] = out;
    bf16x4 ob = { (__bf16)out.x, (__bf16)out.y, (__bf16)out.z, (__bf16)out.w };
    *(bf16x4*)&xbf[off + t * 4] = ob;
}

// ---------------------------------------------------------------------------
extern "C" void kernel_launch(void* const* d_in, const int* in_sizes, int n_in,
                              void* d_out, int out_size, void* d_ws, size_t ws_size,
                              hipStream_t stream) {
    (void)in_sizes; (void)n_in; (void)out_size; (void)ws_size;

    const int*   src  = (const int*)  d_in[0];
    const float* emb  = (const float*)d_in[1];
    const float* Wq   = (const float*)d_in[2];
    const float* bq   = (const float*)d_in[3];
    const float* Wk   = (const float*)d_in[4];
    const float* bk   = (const float*)d_in[5];
    const float* Wv   = (const float*)d_in[6];
    const float* bv   = (const float*)d_in[7];
    const float* Wo   = (const float*)d_in[8];
    const float* bo   = (const float*)d_in[9];
    const float* W1   = (const float*)d_in[10];
    const float* b1   = (const float*)d_in[11];
    const float* W2   = (const float*)d_in[12];
    const float* b2   = (const float*)d_in[13];
    const float* g1   = (const float*)d_in[14];
    const float* be1  = (const float*)d_in[15];
    const float* g3   = (const float*)d_in[16];
    const float* be3  = (const float*)d_in[17];
    const float* Wf   = (const float*)d_in[18];
    const float* bf   = (const float*)d_in[19];

    const size_t MB = 1ull << 20;
    char* w = (char*)d_ws;
    float*  x    = (float*)(w);              // 16 MB [M,D] f32
    float*  pb   = (float*)(w + 16 * MB);    // 16 MB [M,D] f32
    float*  bqkv = (float*)(w + 32 * MB);    // 12 KB packed qkv bias
    __bf16* xbf  = (__bf16*)(w + 33 * MB);   //  8 MB [M,D] bf16
    __bf16* abf  = (__bf16*)(w + 41 * MB);   //  8 MB [M,D] bf16
    __bf16* qkvb = (__bf16*)(w + 49 * MB);   // 24 MB [M,3D] bf16 (aliases f1b)
    __bf16* f1b  = (__bf16*)(w + 49 * MB);   // 32 MB [M,F] bf16
    __bf16* tbuf = (__bf16*)(w + 81 * MB);   // 16 MB transposed-weight buffer

    const dim3 blk(256);

    embed_kernel<<<(M * D + 255) / 256, blk, 0, stream>>>(src, emb, x, xbf);

    for (int l = 0; l < L; ++l) {
        const size_t oDD = (size_t)l * D * D;
        // QKV: pack W^T (bf16) + bias, one fused N=3072 GEMM
        transpose_bf16_kernel<<<dim3(16, 16), blk, 0, stream>>>(Wq + oDD, tbuf,              D, D);
        transpose_bf16_kernel<<<dim3(16, 16), blk, 0, stream>>>(Wk + oDD, tbuf + 1024 * 1024, D, D);
        transpose_bf16_kernel<<<dim3(16, 16), blk, 0, stream>>>(Wv + oDD, tbuf + 2048 * 1024, D, D);
        pack_qkv_bias_kernel<<<12, blk, 0, stream>>>(bq + l * D, bk + l * D, bv + l * D, bqkv);
        mfma_gemm<false, true><<<dim3(24, 32), blk, 0, stream>>>(xbf, tbuf, bqkv, qkvb, 3 * D, D);

        attn_kernel<<<B * H * (S / 64), blk, 0, stream>>>(qkvb, src, abf);

        transpose_bf16_kernel<<<dim3(16, 16), blk, 0, stream>>>(Wo + oDD, tbuf, D, D);
        mfma_gemm<false, false><<<dim3(8, 32), blk, 0, stream>>>(abf, tbuf, bo + l * D, pb, D, D);
        add_ln_kernel<<<M, blk, 0, stream>>>(x, pb, g1 + l * D, be1 + l * D, xbf);

        transpose_bf16_kernel<<<dim3(64, 16), blk, 0, stream>>>(W1 + (size_t)l * D * F, tbuf, D, F);
        mfma_gemm<true, true><<<dim3(32, 32), blk, 0, stream>>>(xbf, tbuf, b1 + l * F, f1b, F, D);

        transpose_bf16_kernel<<<dim3(16, 64), blk, 0, stream>>>(W2 + (size_t)l * F * D, tbuf, F, D);
        mfma_gemm<false, false><<<dim3(8, 32), blk, 0, stream>>>(f1b, tbuf, b2 + l * D, pb, D, F);
        add_ln_kernel<<<M, blk, 0, stream>>>(x, pb, g3 + l * D, be3 + l * D, xbf);
    }

    transpose_bf16_kernel<<<dim3(128, 16), blk, 0, stream>>>(Wf, tbuf, D, V);
    mfma_gemm<false, false><<<dim3(64, 32), blk, 0, stream>>>(xbf, tbuf, bf, (float*)d_out, V, D);
}

// Round 6
// 1680.089 us; speedup vs baseline: 5.1231x; 1.8960x over previous
//
#include <hip/hip_runtime.h>
#include <hip/hip_bf16.h>
#include <cstddef>
#include <cstdint>

#define B 4
#define S 1024
#define D 1024
#define H 16
#define L 4
#define F 4096
#define V 8192
#define DK 64
#define M (B*S)          // 4096 rows
#define EPS 1e-5f
#define SCALE 0.125f     // 1/sqrt(64)

typedef __bf16 bf16x8 __attribute__((ext_vector_type(8)));
typedef __bf16 bf16x4 __attribute__((ext_vector_type(4)));
typedef float  f32x4  __attribute__((ext_vector_type(4)));

// async global->LDS, 16B per lane; LDS dest = wave-uniform base + lane*16
__device__ __forceinline__ void gload16(const void* g, void* l) {
    __builtin_amdgcn_global_load_lds(
        (const __attribute__((address_space(1))) void*)g,
        (__attribute__((address_space(3))) void*)l, 16, 0, 0);
}

// ---------------------------------------------------------------------------
// Embedding + sinusoidal positional encoding (dual fp32 + bf16 output)
// ---------------------------------------------------------------------------
__global__ void embed_kernel(const int* __restrict__ src,
                             const float* __restrict__ emb,
                             float* __restrict__ x, __bf16* __restrict__ xbf) {
    int idx = blockIdx.x * blockDim.x + threadIdx.x;
    if (idx >= B * S * D) return;
    int d  = idx & (D - 1);
    int bs = idx >> 10;
    int s  = bs & (S - 1);
    int tok = src[bs];
    int d2 = d & ~1;
    float div = expf((float)d2 * (-9.210340371976184f / 1024.0f));
    float arg = (float)s * div;
    float pe = (d & 1) ? cosf(arg) : sinf(arg);
    float v = emb[(size_t)tok * D + d] + pe;
    x[idx] = v;
    xbf[idx] = (__bf16)v;
}

// ---------------------------------------------------------------------------
// fp32 [K][N]  ->  bf16 [N][K]   (weight transpose + downconvert)
// ---------------------------------------------------------------------------
__global__ __launch_bounds__(256) void transpose_bf16_kernel(
        const float* __restrict__ in, __bf16* __restrict__ out, int K, int N) {
    __shared__ float tile[64][65];
    const int n0 = blockIdx.x * 64, k0 = blockIdx.y * 64;
    const int r = threadIdx.x >> 4, c4 = (threadIdx.x & 15) * 4;
    #pragma unroll
    for (int p = 0; p < 4; ++p) {
        float4 v = *(const float4*)&in[(size_t)(k0 + r + p * 16) * N + n0 + c4];
        tile[r + p * 16][c4 + 0] = v.x;
        tile[r + p * 16][c4 + 1] = v.y;
        tile[r + p * 16][c4 + 2] = v.z;
        tile[r + p * 16][c4 + 3] = v.w;
    }
    __syncthreads();
    #pragma unroll
    for (int p = 0; p < 4; ++p) {
        int n = r + p * 16;
        bf16x4 o = { (__bf16)tile[c4 + 0][n], (__bf16)tile[c4 + 1][n],
                     (__bf16)tile[c4 + 2][n], (__bf16)tile[c4 + 3][n] };
        *(bf16x4*)&out[(size_t)(n0 + n) * K + k0 + c4] = o;
    }
}

__global__ void pack_qkv_bias_kernel(const float* __restrict__ bq,
                                     const float* __restrict__ bk,
                                     const float* __restrict__ bv,
                                     float* __restrict__ o) {
    int i = blockIdx.x * 256 + threadIdx.x;
    if (i >= 3 * D) return;
    o[i] = (i < D) ? bq[i] : (i < 2 * D) ? bk[i - D] : bv[i - 2 * D];
}

// ---------------------------------------------------------------------------
// MFMA bf16 GEMM (m97 structure): C[M,N] = A[M,K] @ BT[N,K]^T + bias
// ---------------------------------------------------------------------------
template<bool RELU, bool OBF>
__global__ __launch_bounds__(256) void mfma_gemm(
        const __bf16* __restrict__ A, const __bf16* __restrict__ BT,
        const float* __restrict__ bias, void* __restrict__ Cout,
        int N, int K) {
    __shared__ __bf16 Asl[128 * 32];
    __shared__ __bf16 Bsl[128 * 32];

    const int tid = threadIdx.x;
    const int bn = blockIdx.x, bm = blockIdx.y;
    const int wv = tid >> 6, ln = tid & 63;
    const int wr = wv >> 1, wc = wv & 1;
    const int fr = ln & 15, kq = ln >> 4;

    const __bf16* Ag = A + (size_t)(bm * 128 + (tid >> 2)) * K + (tid & 3) * 8;
    const __bf16* Bg = BT + (size_t)(bn * 128 + (tid >> 2)) * K + (tid & 3) * 8;
    char* AsW = (char*)Asl + wv * 1024;
    char* BsW = (char*)Bsl + wv * 1024;

    f32x4 acc[4][4];
    #pragma unroll
    for (int i = 0; i < 4; ++i)
        #pragma unroll
        for (int j = 0; j < 4; ++j) acc[i][j] = f32x4{0.f, 0.f, 0.f, 0.f};

    const size_t K64 = (size_t)64 * K;
    for (int k0 = 0; k0 < K; k0 += 32) {
        __syncthreads();
        gload16(Ag + k0,       AsW);
        gload16(Ag + K64 + k0, AsW + 4096);
        gload16(Bg + k0,       BsW);
        gload16(Bg + K64 + k0, BsW + 4096);
        __syncthreads();

        bf16x8 af[4], bfr[4];
        const char* Ab = (const char*)Asl;
        const char* Bb = (const char*)Bsl;
        #pragma unroll
        for (int mi = 0; mi < 4; ++mi)
            af[mi] = *(const bf16x8*)(Ab + (wr * 64 + mi * 16 + fr) * 64 + kq * 16);
        #pragma unroll
        for (int ni = 0; ni < 4; ++ni)
            bfr[ni] = *(const bf16x8*)(Bb + (wc * 64 + ni * 16 + fr) * 64 + kq * 16);
        #pragma unroll
        for (int mi = 0; mi < 4; ++mi)
            #pragma unroll
            for (int ni = 0; ni < 4; ++ni)
                acc[mi][ni] = __builtin_amdgcn_mfma_f32_16x16x32_bf16(
                                  af[mi], bfr[ni], acc[mi][ni], 0, 0, 0);
    }

    const int col0 = bn * 128 + wc * 64;
    const int row0 = bm * 128 + wr * 64;
    #pragma unroll
    for (int ni = 0; ni < 4; ++ni) {
        const int col = col0 + ni * 16 + fr;
        const float bia = bias[col];
        #pragma unroll
        for (int mi = 0; mi < 4; ++mi)
            #pragma unroll
            for (int j = 0; j < 4; ++j) {
                const int row = row0 + mi * 16 + kq * 4 + j;
                float v = acc[mi][ni][j] + bia;
                if (RELU) v = fmaxf(v, 0.f);
                if (OBF) ((__bf16*)Cout)[(size_t)row * N + col] = (__bf16)v;
                else     ((float*)Cout)[(size_t)row * N + col] = v;
            }
    }
}

// ---------------------------------------------------------------------------
// MFMA flash attention. Block = (b, h, 128-q-tile), 512 thr = 8 waves,
// wave owns 16 q rows (Q in registers). Per 64-key tile: K in LDS
// (XOR-swizzled), V in LDS transposed [dv][key] (swizzled), S via
// mfma(Q,K^T), in-register online softmax, P->bf16 to wave-private LDS,
// PV via mfma(P,V^T). Causal tile-skip gated on pad rows: a pad row
// (src==0) softmaxes uniformly over ALL keys, so any wave/block holding
// one visits every tile; otherwise tiles with k0 > max q are skipped
// (exact: they contribute p=0). Barrier-safe: block-uniform tile count,
// waves skip compute only.
// ---------------------------------------------------------------------------
__global__ __launch_bounds__(512) void attn_mfma_kernel(
        const __bf16* __restrict__ qkv, const int* __restrict__ src,
        __bf16* __restrict__ ag) {
    __shared__ char lds[32768];
    __shared__ int s_anypad;
    char* Ks = lds;            // 8KB  [key 64][128B], byte ^= (key&7)<<4
    char* VT = lds + 8192;     // 8KB  [dv 64][128B of keys], byte ^= (dv&7)<<4
    char* Ps = lds + 16384;    // 16KB [wave 8][q 16][128B], byte ^= (q&7)<<4

    const int tid  = threadIdx.x;
    const int qt   = blockIdx.x & 7;
    const int h    = (blockIdx.x >> 3) & 15;
    const int b    = blockIdx.x >> 7;
    const int q0   = qt * 128;
    const int w    = tid >> 6, lane = tid & 63;
    const int fr   = lane & 15, kq = lane >> 4;

    const int qoff = h * 64, koff = D + h * 64, voff = 2 * D + h * 64;
    const int RS = 3 * D;

    // Q A-fragments: row = q0 + w*16 + fr, k-slices kq*8 within dk 0..31/32..63
    const size_t qbase = (size_t)(b * S + q0 + w * 16 + fr) * RS + qoff + kq * 8;
    const bf16x8 aq0 = *(const bf16x8*)&qkv[qbase];
    const bf16x8 aq1 = *(const bf16x8*)&qkv[qbase + 32];

    // per-lane C-layout rows: q0 + w*16 + kq*4 + j
    const int qg_base = q0 + w * 16 + kq * 4;
    bool valid[4];
    bool anypad = false;
    #pragma unroll
    for (int j = 0; j < 4; ++j) {
        valid[j] = src[b * S + qg_base + j] != 0;
        anypad |= !valid[j];
    }
    if (tid == 0) s_anypad = 0;
    __syncthreads();
    if (anypad) s_anypad = 1;
    __syncthreads();
    const bool bpad = (s_anypad != 0);
    const bool wpad = __any(anypad) != 0;

    const int kt_blk = bpad ? 16 : (q0 + 127) / 64 + 1;            // 2*qt+2
    const int kt_wav = wpad ? 16 : (q0 + w * 16 + 15) / 64 + 1;

    float m[4]   = {-3.0e38f, -3.0e38f, -3.0e38f, -3.0e38f};
    float lsm[4] = {0.f, 0.f, 0.f, 0.f};
    f32x4 o[4];
    #pragma unroll
    for (int ni = 0; ni < 4; ++ni) o[ni] = f32x4{0.f, 0.f, 0.f, 0.f};

    // staging coords: K by (row=tid>>3, 16B chunk=tid&7) — coalesced;
    // V by (key=tid&63, dv block=(tid>>6)*8) — transpose writes contiguous.
    const int skey = tid >> 3, sck = tid & 7;
    const int vkey = tid & 63, vdvb = (tid >> 6) * 8;

    for (int kt = 0; kt < kt_blk; ++kt) {
        const int k0 = kt * 64;
        __syncthreads();   // all waves done reading Ks/VT of prev tile
        {
            bf16x8 kv8 = *(const bf16x8*)&qkv[(size_t)(b * S + k0 + skey) * RS + koff + sck * 8];
            *(bf16x8*)(Ks + ((skey * 128 + sck * 16) ^ ((skey & 7) << 4))) = kv8;
            bf16x8 vv8 = *(const bf16x8*)&qkv[(size_t)(b * S + k0 + vkey) * RS + voff + vdvb];
            #pragma unroll
            for (int j = 0; j < 8; ++j) {
                int dv = vdvb + j;
                *(__bf16*)(VT + ((dv * 128 + vkey * 2) ^ ((dv & 7) << 4))) = vv8[j];
            }
        }
        __syncthreads();
        if (kt >= kt_wav) continue;   // compute skip only; barriers stay aligned

        // ---- QK^T: S[16 q][64 key] = 4 col-fragments x 2 k-steps
        f32x4 s[4];
        #pragma unroll
        for (int ni = 0; ni < 4; ++ni) s[ni] = f32x4{0.f, 0.f, 0.f, 0.f};
        #pragma unroll
        for (int ni = 0; ni < 4; ++ni) {
            const int kr = ni * 16 + fr;
            const int sw = (kr & 7) << 4;
            bf16x8 bk0 = *(const bf16x8*)(Ks + ((kr * 128 +  0 + kq * 16) ^ sw));
            bf16x8 bk1 = *(const bf16x8*)(Ks + ((kr * 128 + 64 + kq * 16) ^ sw));
            s[ni] = __builtin_amdgcn_mfma_f32_16x16x32_bf16(aq0, bk0, s[ni], 0, 0, 0);
            s[ni] = __builtin_amdgcn_mfma_f32_16x16x32_bf16(aq1, bk1, s[ni], 0, 0, 0);
        }

        // ---- mask + scale (element: q = qg_base+j, key = k0+ni*16+fr)
        #pragma unroll
        for (int ni = 0; ni < 4; ++ni) {
            const int keyg = k0 + ni * 16 + fr;
            #pragma unroll
            for (int j = 0; j < 4; ++j) {
                float sv = s[ni][j] * SCALE;
                s[ni][j] = (valid[j] && keyg <= qg_base + j) ? sv : -1e9f;
            }
        }

        // ---- online softmax per row j; row spread over 16 lanes (bits 0-3)
        #pragma unroll
        for (int j = 0; j < 4; ++j) {
            float t = fmaxf(fmaxf(s[0][j], s[1][j]), fmaxf(s[2][j], s[3][j]));
            t = fmaxf(t, __shfl_xor(t, 1));
            t = fmaxf(t, __shfl_xor(t, 2));
            t = fmaxf(t, __shfl_xor(t, 4));
            t = fmaxf(t, __shfl_xor(t, 8));
            const float mn = fmaxf(m[j], t);
            const float corr = expf(m[j] - mn);
            m[j] = mn;
            float rs = 0.f;
            const int ql = kq * 4 + j;
            const int swp = (ql & 7) << 4;
            #pragma unroll
            for (int ni = 0; ni < 4; ++ni) {
                float p = expf(s[ni][j] - mn);
                rs += p;
                *(__bf16*)(Ps + w * 2048 +
                           ((ql * 128 + (ni * 16 + fr) * 2) ^ swp)) = (__bf16)p;
            }
            rs += __shfl_xor(rs, 1);
            rs += __shfl_xor(rs, 2);
            rs += __shfl_xor(rs, 4);
            rs += __shfl_xor(rs, 8);
            lsm[j] = lsm[j] * corr + rs;
            o[0][j] *= corr; o[1][j] *= corr; o[2][j] *= corr; o[3][j] *= corr;
        }

        // ---- PV: O[16 q][64 dv] += P[16 q][64 key] @ V[key][dv]
        #pragma unroll
        for (int ks = 0; ks < 2; ++ks) {
            bf16x8 ap = *(const bf16x8*)(Ps + w * 2048 +
                          ((fr * 128 + ks * 64 + kq * 16) ^ ((fr & 7) << 4)));
            #pragma unroll
            for (int ni = 0; ni < 4; ++ni) {
                const int dvr = ni * 16 + fr;
                bf16x8 bv = *(const bf16x8*)(VT +
                              ((dvr * 128 + ks * 64 + kq * 16) ^ ((dvr & 7) << 4)));
                o[ni] = __builtin_amdgcn_mfma_f32_16x16x32_bf16(ap, bv, o[ni], 0, 0, 0);
            }
        }
    }

    // ---- epilogue: normalize + store bf16 (16 lanes -> 32B contiguous)
    #pragma unroll
    for (int j = 0; j < 4; ++j) {
        const float inv = 1.0f / lsm[j];
        const size_t rowo = (size_t)(b * S + qg_base + j) * D + h * 64;
        #pragma unroll
        for (int ni = 0; ni < 4; ++ni)
            ag[rowo + ni * 16 + fr] = (__bf16)(o[ni][j] * inv);
    }
}

// ---------------------------------------------------------------------------
// x = LayerNorm(x + r) * g + beta  (in place, fp32) + bf16 copy
// ---------------------------------------------------------------------------
__global__ __launch_bounds__(256) void add_ln_kernel(
        float* __restrict__ x, const float* __restrict__ r,
        const float* __restrict__ g, const float* __restrict__ be,
        __bf16* __restrict__ xbf) {
    __shared__ float red[8];
    const int row = blockIdx.x;
    const size_t off = (size_t)row * D;
    const int t = threadIdx.x;
    const int w = t >> 6, lane = t & 63;

    float4 xv = *(float4*)&x[off + t * 4];
    float4 rv = *(const float4*)&r[off + t * 4];
    float v0 = xv.x + rv.x, v1 = xv.y + rv.y, v2 = xv.z + rv.z, v3 = xv.w + rv.w;

    float s = v0 + v1 + v2 + v3;
    #pragma unroll
    for (int msk = 1; msk < 64; msk <<= 1) s += __shfl_xor(s, msk);
    if (lane == 0) red[w] = s;
    __syncthreads();
    float mean = (red[0] + red[1] + red[2] + red[3]) * (1.0f / D);

    float d0 = v0 - mean, d1 = v1 - mean, d2 = v2 - mean, d3 = v3 - mean;
    float sq = d0 * d0 + d1 * d1 + d2 * d2 + d3 * d3;
    #pragma unroll
    for (int msk = 1; msk < 64; msk <<= 1) sq += __shfl_xor(sq, msk);
    if (lane == 0) red[4 + w] = sq;
    __syncthreads();
    float var = (red[4] + red[5] + red[6] + red[7]) * (1.0f / D);
    float inv = rsqrtf(var + EPS);

    float4 gv = *(const float4*)&g[t * 4];
    float4 bv = *(const float4*)&be[t * 4];
    float4 out;
    out.x = gv.x * d0 * inv + bv.x;
    out.y = gv.y * d1 * inv + bv.y;
    out.z = gv.z * d2 * inv + bv.z;
    out.w = gv.w * d3 * inv + bv.w;
    *(float4*)&x[off + t * 4] = out;
    bf16x4 ob = { (__bf16)out.x, (__bf16)out.y, (__bf16)out.z, (__bf16)out.w };
    *(bf16x4*)&xbf[off + t * 4] = ob;
}

// ---------------------------------------------------------------------------
extern "C" void kernel_launch(void* const* d_in, const int* in_sizes, int n_in,
                              void* d_out, int out_size, void* d_ws, size_t ws_size,
                              hipStream_t stream) {
    (void)in_sizes; (void)n_in; (void)out_size; (void)ws_size;

    const int*   src  = (const int*)  d_in[0];
    const float* emb  = (const float*)d_in[1];
    const float* Wq   = (const float*)d_in[2];
    const float* bq   = (const float*)d_in[3];
    const float* Wk   = (const float*)d_in[4];
    const float* bk   = (const float*)d_in[5];
    const float* Wv   = (const float*)d_in[6];
    const float* bv   = (const float*)d_in[7];
    const float* Wo   = (const float*)d_in[8];
    const float* bo   = (const float*)d_in[9];
    const float* W1   = (const float*)d_in[10];
    const float* b1   = (const float*)d_in[11];
    const float* W2   = (const float*)d_in[12];
    const float* b2   = (const float*)d_in[13];
    const float* g1   = (const float*)d_in[14];
    const float* be1  = (const float*)d_in[15];
    const float* g3   = (const float*)d_in[16];
    const float* be3  = (const float*)d_in[17];
    const float* Wf   = (const float*)d_in[18];
    const float* bf   = (const float*)d_in[19];

    const size_t MB = 1ull << 20;
    char* w = (char*)d_ws;
    float*  x    = (float*)(w);              // 16 MB [M,D] f32
    float*  pb   = (float*)(w + 16 * MB);    // 16 MB [M,D] f32
    float*  bqkv = (float*)(w + 32 * MB);    // 12 KB packed qkv bias
    __bf16* xbf  = (__bf16*)(w + 33 * MB);   //  8 MB [M,D] bf16
    __bf16* abf  = (__bf16*)(w + 41 * MB);   //  8 MB [M,D] bf16
    __bf16* qkvb = (__bf16*)(w + 49 * MB);   // 24 MB [M,3D] bf16 (aliases f1b)
    __bf16* f1b  = (__bf16*)(w + 49 * MB);   // 32 MB [M,F] bf16
    __bf16* tbuf = (__bf16*)(w + 81 * MB);   // 16 MB transposed-weight buffer

    const dim3 blk(256);

    embed_kernel<<<(M * D + 255) / 256, blk, 0, stream>>>(src, emb, x, xbf);

    for (int l = 0; l < L; ++l) {
        const size_t oDD = (size_t)l * D * D;
        transpose_bf16_kernel<<<dim3(16, 16), blk, 0, stream>>>(Wq + oDD, tbuf,               D, D);
        transpose_bf16_kernel<<<dim3(16, 16), blk, 0, stream>>>(Wk + oDD, tbuf + 1024 * 1024, D, D);
        transpose_bf16_kernel<<<dim3(16, 16), blk, 0, stream>>>(Wv + oDD, tbuf + 2048 * 1024, D, D);
        pack_qkv_bias_kernel<<<12, blk, 0, stream>>>(bq + l * D, bk + l * D, bv + l * D, bqkv);
        mfma_gemm<false, true><<<dim3(24, 32), blk, 0, stream>>>(xbf, tbuf, bqkv, qkvb, 3 * D, D);

        attn_mfma_kernel<<<B * H * (S / 128), dim3(512), 0, stream>>>(qkvb, src, abf);

        transpose_bf16_kernel<<<dim3(16, 16), blk, 0, stream>>>(Wo + oDD, tbuf, D, D);
        mfma_gemm<false, false><<<dim3(8, 32), blk, 0, stream>>>(abf, tbuf, bo + l * D, pb, D, D);
        add_ln_kernel<<<M, blk, 0, stream>>>(x, pb, g1 + l * D, be1 + l * D, xbf);

        transpose_bf16_kernel<<<dim3(64, 16), blk, 0, stream>>>(W1 + (size_t)l * D * F, tbuf, D, F);
        mfma_gemm<true, true><<<dim3(32, 32), blk, 0, stream>>>(xbf, tbuf, b1 + l * F, f1b, F, D);

        transpose_bf16_kernel<<<dim3(16, 64), blk, 0, stream>>>(W2 + (size_t)l * F * D, tbuf, F, D);
        mfma_gemm<false, false><<<dim3(8, 32), blk, 0, stream>>>(f1b, tbuf, b2 + l * D, pb, D, F);
        add_ln_kernel<<<M, blk, 0, stream>>>(x, pb, g3 + l * D, be3 + l * D, xbf);
    }

    transpose_bf16_kernel<<<dim3(128, 16), blk, 0, stream>>>(Wf, tbuf, D, V);
    mfma_gemm<false, false><<<dim3(64, 32), blk, 0, stream>>>(xbf, tbuf, bf, (float*)d_out, V, D);
}